// Round 5
// baseline (457.526 us; speedup 1.0000x reference)
//
#include <hip/hip_runtime.h>
#include <hip/hip_bf16.h>
#include <stdint.h>

// SheafAttention on MI355X (gfx950).  B=4, T=2048, D=1024, H=16, S=64.
//
// Pipeline:
//  1. absmax6 (atomicMax on float bits; 0xAA poison is negative int, safe)
//  2. prep_w: quantize wv->W_all[2048:], wo->Wo; fold stalk maps into W_all[0:2048]
//     (Q-part pre-scaled by 0.125*log2e so softmax needs no multiply)
//  3. xcvt: x -> bf16
//  4. gemm128 (global_load_lds w=16, XOR swizzle): QKV = xb @ W_all^T
//  5. vtrans: V part of QKV -> Vt[bh][s][t]
//  6. attn: transposed-score scheme — mfma(K,Q) puts q on lane&15, so P rows pack to
//     ds_write_b64 (4/step vs 16 scalar) and lrun is one scalar/lane. XCD-local pairing.
//  7. gemm128: out = O @ Wo^T (fp32)

typedef __bf16 bf16_t;
typedef __attribute__((ext_vector_type(4))) __bf16 bf16x4;
typedef __attribute__((ext_vector_type(8))) __bf16 bf16x8;
typedef __attribute__((ext_vector_type(4))) float f32x4;

#define BB 4
#define TT 2048
#define DD 1024
#define HH 16
#define SS 64

__device__ __forceinline__ float quant6(float v, float s) {
    float q = rintf(v / s);
    q = fminf(fmaxf(q, -31.0f), 31.0f);
    return q * s;
}

__device__ __forceinline__ float fexp2(float x) {
#if __has_builtin(__builtin_amdgcn_exp2f)
    return __builtin_amdgcn_exp2f(x);
#else
    return exp2f(x);
#endif
}

typedef __attribute__((address_space(3))) uint32_t lds_u32;
typedef const __attribute__((address_space(1))) uint32_t glb_u32;

// ---------------------------------------------------------------- fused absmax (6 tensors)
__global__ __launch_bounds__(256) void absmax6(const float* __restrict__ wq,
                                               const float* __restrict__ wk,
                                               const float* __restrict__ wv,
                                               const float* __restrict__ wo,
                                               const float* __restrict__ wu,
                                               const float* __restrict__ wsv,
                                               float* __restrict__ amax) {
    const int t = blockIdx.y;
    const float* src = (t == 0) ? wq : (t == 1) ? wk : (t == 2) ? wv
                     : (t == 3) ? wo : (t == 4) ? wu : wsv;
    const int n4 = (t < 4) ? (1048576 / 4) : (4096 / 4);
    float m = 0.0f;
    for (int i = blockIdx.x * blockDim.x + threadIdx.x; i < n4; i += gridDim.x * blockDim.x) {
        float4 v = ((const float4*)src)[i];
        m = fmaxf(m, fmaxf(fmaxf(fabsf(v.x), fabsf(v.y)), fmaxf(fabsf(v.z), fabsf(v.w))));
    }
    #pragma unroll
    for (int mask = 32; mask > 0; mask >>= 1)
        m = fmaxf(m, __shfl_xor(m, mask));
    __shared__ float red[4];
    int w = threadIdx.x >> 6;
    if ((threadIdx.x & 63) == 0) red[w] = m;
    __syncthreads();
    if (threadIdx.x == 0) {
        m = fmaxf(fmaxf(red[0], red[1]), fmaxf(red[2], red[3]));
        atomicMax((int*)(amax + t), __float_as_int(m));
    }
}

// ---------------------------------------------------------------- x fp32 -> bf16
__global__ __launch_bounds__(256) void xcvt_kernel(const float* __restrict__ x,
                                                   bf16_t* __restrict__ xb) {
    int i = (blockIdx.x * 256 + threadIdx.x) * 8;
    float4 f0 = *(const float4*)(x + i);
    float4 f1 = *(const float4*)(x + i + 4);
    bf16x8 v;
    v[0] = (bf16_t)f0.x; v[1] = (bf16_t)f0.y; v[2] = (bf16_t)f0.z; v[3] = (bf16_t)f0.w;
    v[4] = (bf16_t)f1.x; v[5] = (bf16_t)f1.y; v[6] = (bf16_t)f1.z; v[7] = (bf16_t)f1.w;
    *(bf16x8*)(xb + i) = v;
}

// ---------------------------------------------------------------- weight prep (quant + fold)
// bx < 512: quantize-cast (y=0: wv -> dv, y=1: wo -> dw)
// bx >= 512: fold stalk map via MFMA (y=0: q(wu)@q(wq[h]) * 0.125*log2e, y=1: q(wsv)@q(wk[h]))
__global__ __launch_bounds__(256) void prep_w(const float* __restrict__ wq,
                                              const float* __restrict__ wk,
                                              const float* __restrict__ wv,
                                              const float* __restrict__ wo,
                                              const float* __restrict__ wu,
                                              const float* __restrict__ wsv,
                                              const float* __restrict__ amax,
                                              bf16_t* __restrict__ W_all,
                                              bf16_t* __restrict__ Wo) {
    const int which = blockIdx.y;
    if (blockIdx.x < 512) {
        const float* src = which ? wo : wv;
        bf16_t* dst = which ? Wo : (W_all + (size_t)2048 * 1024);
        float s = amax[which ? 3 : 2] / 31.0f + 1e-8f;
        int i = (blockIdx.x * 256 + threadIdx.x) * 8;
        float4 f0 = *(const float4*)(src + i);
        float4 f1 = *(const float4*)(src + i + 4);
        bf16x8 v;
        v[0] = (bf16_t)quant6(f0.x, s); v[1] = (bf16_t)quant6(f0.y, s);
        v[2] = (bf16_t)quant6(f0.z, s); v[3] = (bf16_t)quant6(f0.w, s);
        v[4] = (bf16_t)quant6(f1.x, s); v[5] = (bf16_t)quant6(f1.y, s);
        v[6] = (bf16_t)quant6(f1.z, s); v[7] = (bf16_t)quant6(f1.w, s);
        *(bf16x8*)(dst + i) = v;
        return;
    }
    const int fx = blockIdx.x - 512;
    const float* wbig = which ? wk : wq;
    const float* wsml = which ? wsv : wu;
    const float sb = amax[which ? 1 : 0] / 31.0f + 1e-8f;
    const float ss = amax[which ? 5 : 4] / 31.0f + 1e-8f;
    const float oscale = which ? 1.0f : 0.125f * 1.44269504089f;
    bf16_t* outp = W_all + (size_t)which * 1024 * 1024;
    const int h = fx >> 4, n0 = (fx & 15) * 64;
    const int w = threadIdx.x >> 6, l = threadIdx.x & 63;
    const int l15 = l & 15, quad = l >> 4, q8 = quad * 8;
    const int m0 = w * 16;

    bf16x8 af[2];
    #pragma unroll
    for (int kc = 0; kc < 2; ++kc) {
        const float* src = wsml + (m0 + l15) * 64 + kc * 32 + q8;
        float4 f0 = *(const float4*)(src);
        float4 f1 = *(const float4*)(src + 4);
        bf16x8 a;
        a[0] = (bf16_t)quant6(f0.x, ss); a[1] = (bf16_t)quant6(f0.y, ss);
        a[2] = (bf16_t)quant6(f0.z, ss); a[3] = (bf16_t)quant6(f0.w, ss);
        a[4] = (bf16_t)quant6(f1.x, ss); a[5] = (bf16_t)quant6(f1.y, ss);
        a[6] = (bf16_t)quant6(f1.z, ss); a[7] = (bf16_t)quant6(f1.w, ss);
        af[kc] = a;
    }
    f32x4 acc[4];
    #pragma unroll
    for (int nb = 0; nb < 4; ++nb) acc[nb] = (f32x4){0.f, 0.f, 0.f, 0.f};
    #pragma unroll
    for (int kc = 0; kc < 2; ++kc) {
        #pragma unroll
        for (int nb = 0; nb < 4; ++nb) {
            bf16x8 bfr;
            #pragma unroll
            for (int j = 0; j < 8; ++j)
                bfr[j] = (bf16_t)quant6(wbig[(size_t)(h * 64 + kc * 32 + q8 + j) * 1024 + n0 + nb * 16 + l15], sb);
            acc[nb] = __builtin_amdgcn_mfma_f32_16x16x32_bf16(af[kc], bfr, acc[nb], 0, 0, 0);
        }
    }
    #pragma unroll
    for (int nb = 0; nb < 4; ++nb)
        #pragma unroll
        for (int r = 0; r < 4; ++r)
            outp[(size_t)(h * 64 + m0 + quad * 4 + r) * 1024 + n0 + nb * 16 + l15] =
                (bf16_t)(acc[nb][r] * oscale);
}

// ---------------------------------------------------------------- GEMM  C[M,N] = A[M,K] * Bt[N,K]^T
template <bool OUT_F32>
__global__ __launch_bounds__(256) void gemm128(const bf16_t* __restrict__ A,
                                               const bf16_t* __restrict__ Bt,
                                               void* __restrict__ Cv,
                                               int lda, int ldb, int ldc, int K) {
    __shared__ __align__(16) bf16_t As[128 * 64];
    __shared__ __align__(16) bf16_t Bs[128 * 64];
    const int tid = threadIdx.x;
    const int w = tid >> 6, l = tid & 63;
    const int l15 = l & 15, quad = l >> 4;
    const int m0 = blockIdx.y * 128, n0 = blockIdx.x * 128;
    const int wm = (w & 1) * 64, wn = (w >> 1) * 64;

    f32x4 acc[4][4];
    #pragma unroll
    for (int a = 0; a < 4; ++a)
        #pragma unroll
        for (int b = 0; b < 4; ++b) acc[a][b] = (f32x4){0.f, 0.f, 0.f, 0.f};

    for (int kc = 0; kc < K; kc += 64) {
        __syncthreads();
        #pragma unroll
        for (int rep = 0; rep < 4; ++rep) {
            int ci = rep * 256 + w * 64 + l;
            int row = ci >> 3, slot = ci & 7;
            int gch = slot ^ ((row ^ (row >> 3)) & 7);
            __builtin_amdgcn_global_load_lds(
                (glb_u32*)(A + (size_t)(m0 + row) * lda + kc + gch * 8),
                (lds_u32*)(As + (rep * 256 + w * 64) * 8), 16, 0, 0);
            __builtin_amdgcn_global_load_lds(
                (glb_u32*)(Bt + (size_t)(n0 + row) * ldb + kc + gch * 8),
                (lds_u32*)(Bs + (rep * 256 + w * 64) * 8), 16, 0, 0);
        }
        __syncthreads();
        #pragma unroll
        for (int kb = 0; kb < 2; ++kb) {
            bf16x8 af[4], bfr[4];
            #pragma unroll
            for (int mb = 0; mb < 4; ++mb) {
                int row = wm + mb * 16 + l15;
                int slot = ((kb << 2) + quad) ^ ((row ^ (row >> 3)) & 7);
                af[mb] = *(const bf16x8*)(As + (row << 6) + slot * 8);
            }
            #pragma unroll
            for (int nb = 0; nb < 4; ++nb) {
                int row = wn + nb * 16 + l15;
                int slot = ((kb << 2) + quad) ^ ((row ^ (row >> 3)) & 7);
                bfr[nb] = *(const bf16x8*)(Bs + (row << 6) + slot * 8);
            }
            #pragma unroll
            for (int mb = 0; mb < 4; ++mb)
                #pragma unroll
                for (int nb = 0; nb < 4; ++nb)
                    acc[mb][nb] = __builtin_amdgcn_mfma_f32_16x16x32_bf16(af[mb], bfr[nb], acc[mb][nb], 0, 0, 0);
        }
    }
    #pragma unroll
    for (int mb = 0; mb < 4; ++mb) {
        #pragma unroll
        for (int nb = 0; nb < 4; ++nb) {
            int col = n0 + wn + nb * 16 + l15;
            #pragma unroll
            for (int r = 0; r < 4; ++r) {
                int row = m0 + wm + mb * 16 + quad * 4 + r;
                if constexpr (OUT_F32)
                    ((float*)Cv)[(size_t)row * ldc + col] = acc[mb][nb][r];
                else
                    ((bf16_t*)Cv)[(size_t)row * ldc + col] = (bf16_t)acc[mb][nb][r];
            }
        }
    }
}

// ---------------------------------------------------------------- V transpose: QKV V-part -> Vt[bh][s][t]
__global__ __launch_bounds__(256) void vtrans_kernel(const bf16_t* __restrict__ QKV,
                                                     bf16_t* __restrict__ Vt) {
    __shared__ __align__(16) bf16_t tile[64 * 72];
    const int tid = threadIdx.x;
    const int bh = blockIdx.x >> 5, tt = blockIdx.x & 31;
    const int b = bh >> 4, h = bh & 15;
    #pragma unroll
    for (int rep = 0; rep < 2; ++rep) {
        int ci = rep * 256 + tid;
        int row = ci >> 3, ch = ci & 7;
        bf16x8 v = *(const bf16x8*)(QKV + ((size_t)(b * TT + tt * 64 + row)) * 3072 + 2048 + h * 64 + ch * 8);
        #pragma unroll
        for (int j = 0; j < 8; ++j) tile[(ch * 8 + j) * 72 + row] = v[j];
    }
    __syncthreads();
    #pragma unroll
    for (int rep = 0; rep < 2; ++rep) {
        int ci = rep * 256 + tid;
        int s = ci >> 3, ch = ci & 7;
        bf16x8 v = *(const bf16x8*)(tile + s * 72 + ch * 8);
        *(bf16x8*)(Vt + ((size_t)(bh * 64 + s)) * TT + tt * 64 + ch * 8) = v;
    }
}

// ---------------------------------------------------------------- attention (transposed scores)
// Sᵀ = mfma(K, Q): lane holds S[q = l15][kpos = c*16 + quad*4 + r].
// P row q packs 4 consecutive kpos -> one ds_write_b64; A-frag read is ds_read_b128.
// 16B-block swizzle: block p' = p ^ (l15&7) keeps banks <=2-way (free).
__device__ __forceinline__ void attn_step(bf16_t* __restrict__ Pw,
                                          const bf16x8 kb[4][2], const bf16x8 vb[4][2],
                                          const bf16x8 qa[2],
                                          f32x4* oacc, float& lrun,
                                          int qlane, int kbase, bool diag, float pb2,
                                          int l15, int quad) {
    f32x4 sacc[4];
    #pragma unroll
    for (int c = 0; c < 4; ++c) sacc[c] = (f32x4){0.f, 0.f, 0.f, 0.f};
    #pragma unroll
    for (int kc = 0; kc < 2; ++kc)
        #pragma unroll
        for (int c = 0; c < 4; ++c)
            sacc[c] = __builtin_amdgcn_mfma_f32_16x16x32_bf16(kb[c][kc], qa[kc], sacc[c], 0, 0, 0);

    const int kp0 = kbase + quad * 4;
    #pragma unroll
    for (int c = 0; c < 4; ++c) {
        bf16x4 pk;
        #pragma unroll
        for (int r = 0; r < 4; ++r) {
            const int k = kp0 + c * 16 + r;
            const int d = qlane - k;
            float ctzf = (float)__builtin_ctz((unsigned)d | 0x10000u);  // d==0 -> 16 -> bias 1.0
            float s2 = sacc[c][r] + pb2 * ctzf;                          // Q pre-scaled by 0.125*log2e
            if (diag && k > qlane) s2 = -INFINITY;
            float p = fexp2(s2);
            lrun += p;
            pk[r] = (bf16_t)p;
        }
        int pp = (c * 2 + (quad >> 1)) ^ (l15 & 7);
        *(bf16x4*)(Pw + l15 * 64 + pp * 8 + (quad & 1) * 4) = pk;
    }
    __builtin_amdgcn_wave_barrier();
    #pragma unroll
    for (int kc = 0; kc < 2; ++kc) {
        bf16x8 pa = *(const bf16x8*)(Pw + l15 * 64 + (((kc * 4 + quad) ^ (l15 & 7)) * 8));
        #pragma unroll
        for (int sb = 0; sb < 4; ++sb)
            oacc[sb] = __builtin_amdgcn_mfma_f32_16x16x32_bf16(pa, vb[sb][kc], oacc[sb], 0, 0, 0);
    }
    __builtin_amdgcn_wave_barrier();
}

// Block = (bh, pair): Q-tiles {pair, 31-pair}. XCD decode keeps all 16 pair-blocks of a bh
// on one XCD and in one 128-block dispatch window.
__global__ __launch_bounds__(256, 4) void attn_kernel(const bf16_t* __restrict__ QKV,
                                                      const bf16_t* __restrict__ Vt,
                                                      const float* __restrict__ p_scale_ptr,
                                                      bf16_t* __restrict__ O) {
    __shared__ __align__(16) bf16_t Ks[64 * 64];
    __shared__ __align__(16) bf16_t Vs[64 * 64];
    __shared__ __align__(16) bf16_t Ps[4 * 16 * 64];

    const int tid = threadIdx.x;
    const int w = tid >> 6, l = tid & 63;
    const int l15 = l & 15, quad = l >> 4, q8 = quad * 8;
    const int pair = (blockIdx.x >> 3) & 15;
    const int bh = (blockIdx.x & 7) + ((blockIdx.x >> 7) << 3);
    const int b = bh >> 4, h = bh & 15;
    const int qtA = pair, qtB = 31 - pair;
    const int q0A = qtA * 64 + w * 16, q0B = qtB * 64 + w * 16;
    const int qlA = q0A + l15, qlB = q0B + l15;

    const float pb2 = p_scale_ptr[0] * 1.44269504089f * 0.0625f;
    const size_t xbase = (size_t)b * TT * 3072;

    bf16x8 qaA[2], qaB[2];
    #pragma unroll
    for (int kc = 0; kc < 2; ++kc) {
        qaA[kc] = *(const bf16x8*)(QKV + xbase + (size_t)(q0A + l15) * 3072 + h * 64 + kc * 32 + q8);
        qaB[kc] = *(const bf16x8*)(QKV + xbase + (size_t)(q0B + l15) * 3072 + h * 64 + kc * 32 + q8);
    }

    f32x4 oA[4], oB[4];
    float lA = 0.f, lB = 0.f;
    #pragma unroll
    for (int i = 0; i < 4; ++i) {
        oA[i] = (f32x4){0.f, 0.f, 0.f, 0.f};
        oB[i] = (f32x4){0.f, 0.f, 0.f, 0.f};
    }
    bf16_t* Pw = Ps + w * 1024;

    for (int kt = 0; kt <= qtB; ++kt) {
        const int kbase = kt * 64;
        __syncthreads();
        #pragma unroll
        for (int rep = 0; rep < 2; ++rep) {
            int ci = rep * 256 + tid;
            int row = ci >> 3, slot = ci & 7;
            int gch = slot ^ ((row ^ (row >> 3)) & 7);
            __builtin_amdgcn_global_load_lds(
                (glb_u32*)(QKV + xbase + (size_t)(kbase + row) * 3072 + 1024 + h * 64 + gch * 8),
                (lds_u32*)(Ks + (rep * 256 + w * 64) * 8), 16, 0, 0);
            __builtin_amdgcn_global_load_lds(
                (glb_u32*)(Vt + (size_t)bh * 131072 + (size_t)row * 2048 + kbase + gch * 8),
                (lds_u32*)(Vs + (rep * 256 + w * 64) * 8), 16, 0, 0);
        }
        __syncthreads();
        // K/V fragments once per k-tile, shared by both Q-tiles
        bf16x8 kb[4][2], vb[4][2];
        #pragma unroll
        for (int kc = 0; kc < 2; ++kc) {
            #pragma unroll
            for (int c = 0; c < 4; ++c) {
                int row = c * 16 + l15;
                int slot = (kc * 4 + quad) ^ ((row ^ (row >> 3)) & 7);
                kb[c][kc] = *(const bf16x8*)(Ks + row * 64 + slot * 8);
                vb[c][kc] = *(const bf16x8*)(Vs + row * 64 + slot * 8);
            }
        }
        attn_step(Pw, kb, vb, qaB, oB, lB, qlB, kbase, kt == qtB, pb2, l15, quad);
        if (kt <= qtA)
            attn_step(Pw, kb, vb, qaA, oA, lA, qlA, kbase, kt == qtA, pb2, l15, quad);
    }

    // epilogue: lrun is per-lane (q = l15); reduce across quads, broadcast per output row
    #pragma unroll
    for (int t = 0; t < 2; ++t) {
        float s = t ? lB : lA;
        f32x4* oo = t ? oB : oA;
        int q0 = t ? q0B : q0A;
        s += __shfl_xor(s, 16);
        s += __shfl_xor(s, 32);
        float inv = 1.0f / s;
        #pragma unroll
        for (int r = 0; r < 4; ++r) {
            float invr = __shfl(inv, quad * 4 + r);   // lane with l15 == quad*4+r (quad 0 group)
            #pragma unroll
            for (int sb = 0; sb < 4; ++sb) {
                int q = q0 + quad * 4 + r;
                int col = h * 64 + sb * 16 + l15;
                O[(size_t)(b * TT + q) * DD + col] = (bf16_t)(oo[sb][r] * invr);
            }
        }
    }
}

// ---------------------------------------------------------------- launch
extern "C" void kernel_launch(void* const* d_in, const int* in_sizes, int n_in,
                              void* d_out, int out_size, void* d_ws, size_t ws_size,
                              hipStream_t stream) {
    const float* x   = (const float*)d_in[0];
    const float* wq  = (const float*)d_in[1];
    const float* wk  = (const float*)d_in[2];
    const float* wv  = (const float*)d_in[3];
    const float* wo  = (const float*)d_in[4];
    const float* wu  = (const float*)d_in[5];
    const float* wsv = (const float*)d_in[6];
    const float* psc = (const float*)d_in[7];
    float* out = (float*)d_out;

    char* ws = (char*)d_ws;
    float*  amax  = (float*)(ws);
    bf16_t* W_all = (bf16_t*)(ws + 256);                       // 3072x1024 bf16 (6291456 B)
    bf16_t* Wo    = (bf16_t*)(ws + 6291712);                   // 1024x1024 bf16 (2097152 B)
    bf16_t* xb    = (bf16_t*)(ws + 8388864);                   // 8192x1024 bf16 (16777216 B)
    bf16_t* Obuf  = xb;                                        // reuse: xb dead after GEMM1
    bf16_t* QKV   = (bf16_t*)(ws + 25166080);                  // 8192x3072 bf16 (50331648 B)
    bf16_t* Vt    = (bf16_t*)(ws + 75497728);                  // 64bh x 64s x 2048t bf16

    hipLaunchKernelGGL(absmax6, dim3(64, 6), dim3(256), 0, stream, wq, wk, wv, wo, wu, wsv, amax);
    hipLaunchKernelGGL(prep_w, dim3(768, 2), dim3(256), 0, stream,
                       wq, wk, wv, wo, wu, wsv, amax, W_all, Wo);
    hipLaunchKernelGGL(xcvt_kernel, dim3(4096), dim3(256), 0, stream, x, xb);

    // GEMM1: QKV = xb @ W_all^T   (M=8192, N=3072, K=1024)
    hipLaunchKernelGGL((gemm128<false>), dim3(24, 64), dim3(256), 0, stream,
                       xb, W_all, (void*)QKV, 1024, 1024, 3072, 1024);

    // V transpose
    hipLaunchKernelGGL(vtrans_kernel, dim3(2048), dim3(256), 0, stream, QKV, Vt);

    // attention (1024 blocks, XCD-swizzled)
    hipLaunchKernelGGL(attn_kernel, dim3(1024), dim3(256), 0, stream, QKV, Vt, psc, Obuf);

    // GEMM2: out = O @ Wo^T   (M=8192, N=1024, K=1024)
    hipLaunchKernelGGL((gemm128<true>), dim3(8, 64), dim3(256), 0, stream,
                       Obuf, Wo, (void*)out, 1024, 1024, 1024, 1024);
}

// Round 6
// 285.489 us; speedup vs baseline: 1.6026x; 1.6026x over previous
//
#include <hip/hip_runtime.h>
#include <hip/hip_bf16.h>
#include <stdint.h>

// SheafAttention on MI355X (gfx950).  B=4, T=2048, D=1024, H=16, S=64.
//
// Pipeline:
//  1. absmax6 (atomicMax on float bits; 0xAA poison is negative int, safe)
//  2. prep_w: quantize wv->W_all[2048:], wo->Wo; fold stalk maps into W_all[0:2048]
//     (Q-part pre-scaled by 0.125*log2e so softmax needs no multiply)
//  3. xcvt: x -> bf16
//  4. gemm128 (global_load_lds w=16, XOR swizzle): QKV = xb @ W_all^T
//  5. vtrans: V part of QKV -> Vt[bh][s][t]
//  6. attn: transposed-score scheme — mfma(K,Q) puts q on lane&15, so P rows pack to
//     ds_write_b64 (4/step vs 16 scalar) and lrun is one scalar/lane. XCD-local pairing.
//     NOTE: launch_bounds min-waves MUST stay 2 — 4 forces a 128-VGPR cap and the kernel
//     (~160 VGPRs live) spills to scratch: R5 measured WRITE_SIZE 16->460 MB, attn 98->250us.
//  7. gemm128: out = O @ Wo^T (fp32)

typedef __bf16 bf16_t;
typedef __attribute__((ext_vector_type(4))) __bf16 bf16x4;
typedef __attribute__((ext_vector_type(8))) __bf16 bf16x8;
typedef __attribute__((ext_vector_type(4))) float f32x4;

#define BB 4
#define TT 2048
#define DD 1024
#define HH 16
#define SS 64

__device__ __forceinline__ float quant6(float v, float s) {
    float q = rintf(v / s);
    q = fminf(fmaxf(q, -31.0f), 31.0f);
    return q * s;
}

__device__ __forceinline__ float fexp2(float x) {
#if __has_builtin(__builtin_amdgcn_exp2f)
    return __builtin_amdgcn_exp2f(x);
#else
    return exp2f(x);
#endif
}

typedef __attribute__((address_space(3))) uint32_t lds_u32;
typedef const __attribute__((address_space(1))) uint32_t glb_u32;

// ---------------------------------------------------------------- fused absmax (6 tensors)
__global__ __launch_bounds__(256) void absmax6(const float* __restrict__ wq,
                                               const float* __restrict__ wk,
                                               const float* __restrict__ wv,
                                               const float* __restrict__ wo,
                                               const float* __restrict__ wu,
                                               const float* __restrict__ wsv,
                                               float* __restrict__ amax) {
    const int t = blockIdx.y;
    const float* src = (t == 0) ? wq : (t == 1) ? wk : (t == 2) ? wv
                     : (t == 3) ? wo : (t == 4) ? wu : wsv;
    const int n4 = (t < 4) ? (1048576 / 4) : (4096 / 4);
    float m = 0.0f;
    for (int i = blockIdx.x * blockDim.x + threadIdx.x; i < n4; i += gridDim.x * blockDim.x) {
        float4 v = ((const float4*)src)[i];
        m = fmaxf(m, fmaxf(fmaxf(fabsf(v.x), fabsf(v.y)), fmaxf(fabsf(v.z), fabsf(v.w))));
    }
    #pragma unroll
    for (int mask = 32; mask > 0; mask >>= 1)
        m = fmaxf(m, __shfl_xor(m, mask));
    __shared__ float red[4];
    int w = threadIdx.x >> 6;
    if ((threadIdx.x & 63) == 0) red[w] = m;
    __syncthreads();
    if (threadIdx.x == 0) {
        m = fmaxf(fmaxf(red[0], red[1]), fmaxf(red[2], red[3]));
        atomicMax((int*)(amax + t), __float_as_int(m));
    }
}

// ---------------------------------------------------------------- x fp32 -> bf16
__global__ __launch_bounds__(256) void xcvt_kernel(const float* __restrict__ x,
                                                   bf16_t* __restrict__ xb) {
    int i = (blockIdx.x * 256 + threadIdx.x) * 8;
    float4 f0 = *(const float4*)(x + i);
    float4 f1 = *(const float4*)(x + i + 4);
    bf16x8 v;
    v[0] = (bf16_t)f0.x; v[1] = (bf16_t)f0.y; v[2] = (bf16_t)f0.z; v[3] = (bf16_t)f0.w;
    v[4] = (bf16_t)f1.x; v[5] = (bf16_t)f1.y; v[6] = (bf16_t)f1.z; v[7] = (bf16_t)f1.w;
    *(bf16x8*)(xb + i) = v;
}

// ---------------------------------------------------------------- weight prep (quant + fold)
__global__ __launch_bounds__(256) void prep_w(const float* __restrict__ wq,
                                              const float* __restrict__ wk,
                                              const float* __restrict__ wv,
                                              const float* __restrict__ wo,
                                              const float* __restrict__ wu,
                                              const float* __restrict__ wsv,
                                              const float* __restrict__ amax,
                                              bf16_t* __restrict__ W_all,
                                              bf16_t* __restrict__ Wo) {
    const int which = blockIdx.y;
    if (blockIdx.x < 512) {
        const float* src = which ? wo : wv;
        bf16_t* dst = which ? Wo : (W_all + (size_t)2048 * 1024);
        float s = amax[which ? 3 : 2] / 31.0f + 1e-8f;
        int i = (blockIdx.x * 256 + threadIdx.x) * 8;
        float4 f0 = *(const float4*)(src + i);
        float4 f1 = *(const float4*)(src + i + 4);
        bf16x8 v;
        v[0] = (bf16_t)quant6(f0.x, s); v[1] = (bf16_t)quant6(f0.y, s);
        v[2] = (bf16_t)quant6(f0.z, s); v[3] = (bf16_t)quant6(f0.w, s);
        v[4] = (bf16_t)quant6(f1.x, s); v[5] = (bf16_t)quant6(f1.y, s);
        v[6] = (bf16_t)quant6(f1.z, s); v[7] = (bf16_t)quant6(f1.w, s);
        *(bf16x8*)(dst + i) = v;
        return;
    }
    const int fx = blockIdx.x - 512;
    const float* wbig = which ? wk : wq;
    const float* wsml = which ? wsv : wu;
    const float sb = amax[which ? 1 : 0] / 31.0f + 1e-8f;
    const float ss = amax[which ? 5 : 4] / 31.0f + 1e-8f;
    const float oscale = which ? 1.0f : 0.125f * 1.44269504089f;
    bf16_t* outp = W_all + (size_t)which * 1024 * 1024;
    const int h = fx >> 4, n0 = (fx & 15) * 64;
    const int w = threadIdx.x >> 6, l = threadIdx.x & 63;
    const int l15 = l & 15, quad = l >> 4, q8 = quad * 8;
    const int m0 = w * 16;

    bf16x8 af[2];
    #pragma unroll
    for (int kc = 0; kc < 2; ++kc) {
        const float* src = wsml + (m0 + l15) * 64 + kc * 32 + q8;
        float4 f0 = *(const float4*)(src);
        float4 f1 = *(const float4*)(src + 4);
        bf16x8 a;
        a[0] = (bf16_t)quant6(f0.x, ss); a[1] = (bf16_t)quant6(f0.y, ss);
        a[2] = (bf16_t)quant6(f0.z, ss); a[3] = (bf16_t)quant6(f0.w, ss);
        a[4] = (bf16_t)quant6(f1.x, ss); a[5] = (bf16_t)quant6(f1.y, ss);
        a[6] = (bf16_t)quant6(f1.z, ss); a[7] = (bf16_t)quant6(f1.w, ss);
        af[kc] = a;
    }
    f32x4 acc[4];
    #pragma unroll
    for (int nb = 0; nb < 4; ++nb) acc[nb] = (f32x4){0.f, 0.f, 0.f, 0.f};
    #pragma unroll
    for (int kc = 0; kc < 2; ++kc) {
        #pragma unroll
        for (int nb = 0; nb < 4; ++nb) {
            bf16x8 bfr;
            #pragma unroll
            for (int j = 0; j < 8; ++j)
                bfr[j] = (bf16_t)quant6(wbig[(size_t)(h * 64 + kc * 32 + q8 + j) * 1024 + n0 + nb * 16 + l15], sb);
            acc[nb] = __builtin_amdgcn_mfma_f32_16x16x32_bf16(af[kc], bfr, acc[nb], 0, 0, 0);
        }
    }
    #pragma unroll
    for (int nb = 0; nb < 4; ++nb)
        #pragma unroll
        for (int r = 0; r < 4; ++r)
            outp[(size_t)(h * 64 + m0 + quad * 4 + r) * 1024 + n0 + nb * 16 + l15] =
                (bf16_t)(acc[nb][r] * oscale);
}

// ---------------------------------------------------------------- GEMM  C[M,N] = A[M,K] * Bt[N,K]^T
template <bool OUT_F32>
__global__ __launch_bounds__(256) void gemm128(const bf16_t* __restrict__ A,
                                               const bf16_t* __restrict__ Bt,
                                               void* __restrict__ Cv,
                                               int lda, int ldb, int ldc, int K) {
    __shared__ __align__(16) bf16_t As[128 * 64];
    __shared__ __align__(16) bf16_t Bs[128 * 64];
    const int tid = threadIdx.x;
    const int w = tid >> 6, l = tid & 63;
    const int l15 = l & 15, quad = l >> 4;
    const int m0 = blockIdx.y * 128, n0 = blockIdx.x * 128;
    const int wm = (w & 1) * 64, wn = (w >> 1) * 64;

    f32x4 acc[4][4];
    #pragma unroll
    for (int a = 0; a < 4; ++a)
        #pragma unroll
        for (int b = 0; b < 4; ++b) acc[a][b] = (f32x4){0.f, 0.f, 0.f, 0.f};

    for (int kc = 0; kc < K; kc += 64) {
        __syncthreads();
        #pragma unroll
        for (int rep = 0; rep < 4; ++rep) {
            int ci = rep * 256 + w * 64 + l;
            int row = ci >> 3, slot = ci & 7;
            int gch = slot ^ ((row ^ (row >> 3)) & 7);
            __builtin_amdgcn_global_load_lds(
                (glb_u32*)(A + (size_t)(m0 + row) * lda + kc + gch * 8),
                (lds_u32*)(As + (rep * 256 + w * 64) * 8), 16, 0, 0);
            __builtin_amdgcn_global_load_lds(
                (glb_u32*)(Bt + (size_t)(n0 + row) * ldb + kc + gch * 8),
                (lds_u32*)(Bs + (rep * 256 + w * 64) * 8), 16, 0, 0);
        }
        __syncthreads();
        #pragma unroll
        for (int kb = 0; kb < 2; ++kb) {
            bf16x8 af[4], bfr[4];
            #pragma unroll
            for (int mb = 0; mb < 4; ++mb) {
                int row = wm + mb * 16 + l15;
                int slot = ((kb << 2) + quad) ^ ((row ^ (row >> 3)) & 7);
                af[mb] = *(const bf16x8*)(As + (row << 6) + slot * 8);
            }
            #pragma unroll
            for (int nb = 0; nb < 4; ++nb) {
                int row = wn + nb * 16 + l15;
                int slot = ((kb << 2) + quad) ^ ((row ^ (row >> 3)) & 7);
                bfr[nb] = *(const bf16x8*)(Bs + (row << 6) + slot * 8);
            }
            #pragma unroll
            for (int mb = 0; mb < 4; ++mb)
                #pragma unroll
                for (int nb = 0; nb < 4; ++nb)
                    acc[mb][nb] = __builtin_amdgcn_mfma_f32_16x16x32_bf16(af[mb], bfr[nb], acc[mb][nb], 0, 0, 0);
        }
    }
    #pragma unroll
    for (int mb = 0; mb < 4; ++mb) {
        #pragma unroll
        for (int nb = 0; nb < 4; ++nb) {
            int col = n0 + wn + nb * 16 + l15;
            #pragma unroll
            for (int r = 0; r < 4; ++r) {
                int row = m0 + wm + mb * 16 + quad * 4 + r;
                if constexpr (OUT_F32)
                    ((float*)Cv)[(size_t)row * ldc + col] = acc[mb][nb][r];
                else
                    ((bf16_t*)Cv)[(size_t)row * ldc + col] = (bf16_t)acc[mb][nb][r];
            }
        }
    }
}

// ---------------------------------------------------------------- V transpose: QKV V-part -> Vt[bh][s][t]
__global__ __launch_bounds__(256) void vtrans_kernel(const bf16_t* __restrict__ QKV,
                                                     bf16_t* __restrict__ Vt) {
    __shared__ __align__(16) bf16_t tile[64 * 72];
    const int tid = threadIdx.x;
    const int bh = blockIdx.x >> 5, tt = blockIdx.x & 31;
    const int b = bh >> 4, h = bh & 15;
    #pragma unroll
    for (int rep = 0; rep < 2; ++rep) {
        int ci = rep * 256 + tid;
        int row = ci >> 3, ch = ci & 7;
        bf16x8 v = *(const bf16x8*)(QKV + ((size_t)(b * TT + tt * 64 + row)) * 3072 + 2048 + h * 64 + ch * 8);
        #pragma unroll
        for (int j = 0; j < 8; ++j) tile[(ch * 8 + j) * 72 + row] = v[j];
    }
    __syncthreads();
    #pragma unroll
    for (int rep = 0; rep < 2; ++rep) {
        int ci = rep * 256 + tid;
        int s = ci >> 3, ch = ci & 7;
        bf16x8 v = *(const bf16x8*)(tile + s * 72 + ch * 8);
        *(bf16x8*)(Vt + ((size_t)(bh * 64 + s)) * TT + tt * 64 + ch * 8) = v;
    }
}

// ---------------------------------------------------------------- attention (transposed scores)
// Sᵀ = mfma(K, Q): lane holds S[q = l15][kpos = c*16 + quad*4 + r].
// P row q packs 4 consecutive kpos -> one ds_write_b64; A-frag read is ds_read_b128.
// 16B-block swizzle: block p' = p ^ (l15&7) keeps banks <=2-way (free).
__device__ __forceinline__ void attn_step(bf16_t* __restrict__ Pw,
                                          const bf16x8 kb[4][2], const bf16x8 vb[4][2],
                                          const bf16x8 qa[2],
                                          f32x4* oacc, float& lrun,
                                          int qlane, int kbase, bool diag, float pb2,
                                          int l15, int quad) {
    f32x4 sacc[4];
    #pragma unroll
    for (int c = 0; c < 4; ++c) sacc[c] = (f32x4){0.f, 0.f, 0.f, 0.f};
    #pragma unroll
    for (int kc = 0; kc < 2; ++kc)
        #pragma unroll
        for (int c = 0; c < 4; ++c)
            sacc[c] = __builtin_amdgcn_mfma_f32_16x16x32_bf16(kb[c][kc], qa[kc], sacc[c], 0, 0, 0);

    const int kp0 = kbase + quad * 4;
    #pragma unroll
    for (int c = 0; c < 4; ++c) {
        bf16x4 pk;
        #pragma unroll
        for (int r = 0; r < 4; ++r) {
            const int k = kp0 + c * 16 + r;
            const int d = qlane - k;
            float ctzf = (float)__builtin_ctz((unsigned)d | 0x10000u);  // d==0 -> 16 -> bias 1.0
            float s2 = sacc[c][r] + pb2 * ctzf;                          // Q pre-scaled by 0.125*log2e
            if (diag && k > qlane) s2 = -INFINITY;
            float p = fexp2(s2);
            lrun += p;
            pk[r] = (bf16_t)p;
        }
        int pp = (c * 2 + (quad >> 1)) ^ (l15 & 7);
        *(bf16x4*)(Pw + l15 * 64 + pp * 8 + (quad & 1) * 4) = pk;
    }
    __builtin_amdgcn_wave_barrier();
    #pragma unroll
    for (int kc = 0; kc < 2; ++kc) {
        bf16x8 pa = *(const bf16x8*)(Pw + l15 * 64 + (((kc * 4 + quad) ^ (l15 & 7)) * 8));
        #pragma unroll
        for (int sb = 0; sb < 4; ++sb)
            oacc[sb] = __builtin_amdgcn_mfma_f32_16x16x32_bf16(pa, vb[sb][kc], oacc[sb], 0, 0, 0);
    }
    __builtin_amdgcn_wave_barrier();
}

// Block = (bh, pair): Q-tiles {pair, 31-pair}. XCD decode keeps all 16 pair-blocks of a bh
// on one XCD and in one 128-block dispatch window.
__global__ __launch_bounds__(256, 2) void attn_kernel(const bf16_t* __restrict__ QKV,
                                                      const bf16_t* __restrict__ Vt,
                                                      const float* __restrict__ p_scale_ptr,
                                                      bf16_t* __restrict__ O) {
    __shared__ __align__(16) bf16_t Ks[64 * 64];
    __shared__ __align__(16) bf16_t Vs[64 * 64];
    __shared__ __align__(16) bf16_t Ps[4 * 16 * 64];

    const int tid = threadIdx.x;
    const int w = tid >> 6, l = tid & 63;
    const int l15 = l & 15, quad = l >> 4, q8 = quad * 8;
    const int pair = (blockIdx.x >> 3) & 15;
    const int bh = (blockIdx.x & 7) + ((blockIdx.x >> 7) << 3);
    const int b = bh >> 4, h = bh & 15;
    const int qtA = pair, qtB = 31 - pair;
    const int q0A = qtA * 64 + w * 16, q0B = qtB * 64 + w * 16;
    const int qlA = q0A + l15, qlB = q0B + l15;

    const float pb2 = p_scale_ptr[0] * 1.44269504089f * 0.0625f;
    const size_t xbase = (size_t)b * TT * 3072;

    bf16x8 qaA[2], qaB[2];
    #pragma unroll
    for (int kc = 0; kc < 2; ++kc) {
        qaA[kc] = *(const bf16x8*)(QKV + xbase + (size_t)(q0A + l15) * 3072 + h * 64 + kc * 32 + q8);
        qaB[kc] = *(const bf16x8*)(QKV + xbase + (size_t)(q0B + l15) * 3072 + h * 64 + kc * 32 + q8);
    }

    f32x4 oA[4], oB[4];
    float lA = 0.f, lB = 0.f;
    #pragma unroll
    for (int i = 0; i < 4; ++i) {
        oA[i] = (f32x4){0.f, 0.f, 0.f, 0.f};
        oB[i] = (f32x4){0.f, 0.f, 0.f, 0.f};
    }
    bf16_t* Pw = Ps + w * 1024;

    for (int kt = 0; kt <= qtB; ++kt) {
        const int kbase = kt * 64;
        __syncthreads();
        #pragma unroll
        for (int rep = 0; rep < 2; ++rep) {
            int ci = rep * 256 + tid;
            int row = ci >> 3, slot = ci & 7;
            int gch = slot ^ ((row ^ (row >> 3)) & 7);
            __builtin_amdgcn_global_load_lds(
                (glb_u32*)(QKV + xbase + (size_t)(kbase + row) * 3072 + 1024 + h * 64 + gch * 8),
                (lds_u32*)(Ks + (rep * 256 + w * 64) * 8), 16, 0, 0);
            __builtin_amdgcn_global_load_lds(
                (glb_u32*)(Vt + (size_t)bh * 131072 + (size_t)row * 2048 + kbase + gch * 8),
                (lds_u32*)(Vs + (rep * 256 + w * 64) * 8), 16, 0, 0);
        }
        __syncthreads();
        // K/V fragments once per k-tile, shared by both Q-tiles
        bf16x8 kb[4][2], vb[4][2];
        #pragma unroll
        for (int kc = 0; kc < 2; ++kc) {
            #pragma unroll
            for (int c = 0; c < 4; ++c) {
                int row = c * 16 + l15;
                int slot = (kc * 4 + quad) ^ ((row ^ (row >> 3)) & 7);
                kb[c][kc] = *(const bf16x8*)(Ks + row * 64 + slot * 8);
                vb[c][kc] = *(const bf16x8*)(Vs + row * 64 + slot * 8);
            }
        }
        attn_step(Pw, kb, vb, qaB, oB, lB, qlB, kbase, kt == qtB, pb2, l15, quad);
        if (kt <= qtA)
            attn_step(Pw, kb, vb, qaA, oA, lA, qlA, kbase, kt == qtA, pb2, l15, quad);
    }

    // epilogue: lrun is per-lane (q = l15); reduce across quads, broadcast per output row
    #pragma unroll
    for (int t = 0; t < 2; ++t) {
        float s = t ? lB : lA;
        f32x4* oo = t ? oB : oA;
        int q0 = t ? q0B : q0A;
        s += __shfl_xor(s, 16);
        s += __shfl_xor(s, 32);
        float inv = 1.0f / s;
        #pragma unroll
        for (int r = 0; r < 4; ++r) {
            float invr = __shfl(inv, quad * 4 + r);   // lane with l15 == quad*4+r (quad 0 group)
            #pragma unroll
            for (int sb = 0; sb < 4; ++sb) {
                int q = q0 + quad * 4 + r;
                int col = h * 64 + sb * 16 + l15;
                O[(size_t)(b * TT + q) * DD + col] = (bf16_t)(oo[sb][r] * invr);
            }
        }
    }
}

// ---------------------------------------------------------------- launch
extern "C" void kernel_launch(void* const* d_in, const int* in_sizes, int n_in,
                              void* d_out, int out_size, void* d_ws, size_t ws_size,
                              hipStream_t stream) {
    const float* x   = (const float*)d_in[0];
    const float* wq  = (const float*)d_in[1];
    const float* wk  = (const float*)d_in[2];
    const float* wv  = (const float*)d_in[3];
    const float* wo  = (const float*)d_in[4];
    const float* wu  = (const float*)d_in[5];
    const float* wsv = (const float*)d_in[6];
    const float* psc = (const float*)d_in[7];
    float* out = (float*)d_out;

    char* ws = (char*)d_ws;
    float*  amax  = (float*)(ws);
    bf16_t* W_all = (bf16_t*)(ws + 256);                       // 3072x1024 bf16 (6291456 B)
    bf16_t* Wo    = (bf16_t*)(ws + 6291712);                   // 1024x1024 bf16 (2097152 B)
    bf16_t* xb    = (bf16_t*)(ws + 8388864);                   // 8192x1024 bf16 (16777216 B)
    bf16_t* Obuf  = xb;                                        // reuse: xb dead after GEMM1
    bf16_t* QKV   = (bf16_t*)(ws + 25166080);                  // 8192x3072 bf16 (50331648 B)
    bf16_t* Vt    = (bf16_t*)(ws + 75497728);                  // 64bh x 64s x 2048t bf16

    hipLaunchKernelGGL(absmax6, dim3(64, 6), dim3(256), 0, stream, wq, wk, wv, wo, wu, wsv, amax);
    hipLaunchKernelGGL(prep_w, dim3(768, 2), dim3(256), 0, stream,
                       wq, wk, wv, wo, wu, wsv, amax, W_all, Wo);
    hipLaunchKernelGGL(xcvt_kernel, dim3(4096), dim3(256), 0, stream, x, xb);

    // GEMM1: QKV = xb @ W_all^T   (M=8192, N=3072, K=1024)
    hipLaunchKernelGGL((gemm128<false>), dim3(24, 64), dim3(256), 0, stream,
                       xb, W_all, (void*)QKV, 1024, 1024, 3072, 1024);

    // V transpose
    hipLaunchKernelGGL(vtrans_kernel, dim3(2048), dim3(256), 0, stream, QKV, Vt);

    // attention (1024 blocks, XCD-swizzled)
    hipLaunchKernelGGL(attn_kernel, dim3(1024), dim3(256), 0, stream, QKV, Vt, psc, Obuf);

    // GEMM2: out = O @ Wo^T   (M=8192, N=1024, K=1024)
    hipLaunchKernelGGL((gemm128<true>), dim3(8, 64), dim3(256), 0, stream,
                       Obuf, Wo, (void*)out, 1024, 1024, 1024, 1024);
}